// Round 5
// baseline (2433.172 us; speedup 1.0000x reference)
//
#include <hip/hip_runtime.h>
#include <hip/hip_bf16.h>
#include <float.h>

#define SS 4096
#define EE 64
#define DD 4096
#define CAP 128
#define SE (SS*EE)                    // 262144
#define ROW 8192                      // EE*CAP floats per token row
#define KS 32                         // split-K slices
#define BM 256                        // token tile
#define BK 32                         // k tile
#define XSP (BK + 4)                  // xs row stride: 36 floats = 144B (16B aligned)
#define ZREP 12                       // DIAGNOSTIC: replicate gemm work; all z identical
static const size_t SEC = (size_t)SS * EE * CAP;  // 33554432

typedef unsigned long long u64;
typedef unsigned int u32;

// ---------------- W transpose + zero flag arrays ----------------
__global__ __launch_bounds__(256) void k_transpose(const float* __restrict__ W,
                                                   float* __restrict__ Wt,
                                                   u32* __restrict__ zbase) {
  int gid = blockIdx.x * 256 + threadIdx.x;
  if (gid < 64 + 2 * SS) zbase[gid] = 0u;

  __shared__ float t[64][65];
  int k0 = blockIdx.x * 64;
  int tid = threadIdx.x;
#pragma unroll
  for (int i = 0; i < 4; i++) {
    int f = tid + i * 256;
    int e = f >> 4, c4 = f & 15;
    float4 v = *(const float4*)(W + (size_t)e * DD + k0 + c4 * 4);
    t[e][c4 * 4 + 0] = v.x; t[e][c4 * 4 + 1] = v.y;
    t[e][c4 * 4 + 2] = v.z; t[e][c4 * 4 + 3] = v.w;
  }
  __syncthreads();
#pragma unroll
  for (int i = 0; i < 4; i++) {
    int f = tid + i * 256;
    int r = f >> 4, e4 = f & 15;
    float4 o;
    o.x = t[e4 * 4 + 0][r]; o.y = t[e4 * 4 + 1][r];
    o.z = t[e4 * 4 + 2][r]; o.w = t[e4 * 4 + 3][r];
    *(float4*)(Wt + (size_t)(k0 + r) * 64 + e4 * 4) = o;
  }
}

// ---------------- GEMM v3: BM=256 tokens, acc 8 tokens x 8 experts / thread ----------------
// grid (SS/BM=16, KS=32, ZREP): all z-slices compute & store IDENTICAL values
// (diagnostic replication; deterministic).
__global__ __launch_bounds__(256) void k_gemm(const float* __restrict__ x,
                                              const float* __restrict__ Wt,
                                              float* __restrict__ part) {
  __shared__ float xs[BM][XSP];     // 36.9 KB
  __shared__ float wsh[BK][EE];     // 8 KB
  int tb = blockIdx.x;   // token tile (256 tokens)
  int ks = blockIdx.y;   // k slice (128 wide)
  int tid = threadIdx.x;
  int tx = tid & 7;      // expert octet
  int ty = tid >> 3;     // 0..31, token stride 32
  float acc[8][8] = {};
  const int KSL = DD / KS;          // 128
#pragma unroll 1
  for (int kt = 0; kt < KSL / BK; kt++) {   // 4 tiles
    int k0 = ks * KSL + kt * BK;
    // stage x: 256x32 floats, 8 float4/thread
#pragma unroll
    for (int i = 0; i < 8; i++) {
      int f = tid + i * 256;        // quad index 0..2047
      int r = f >> 3, c4 = f & 7;
      *(float4*)&xs[r][c4 * 4] =
          *(const float4*)(x + (size_t)(tb * BM + r) * DD + k0 + c4 * 4);
    }
    // stage w: 32x64 floats, 2 float4/thread
#pragma unroll
    for (int i = 0; i < 2; i++) {
      int f = tid + i * 256;        // quad index 0..511
      int r = f >> 4, c4 = f & 15;
      *(float4*)&wsh[r][c4 * 4] = *(const float4*)(Wt + (size_t)(k0 + r) * EE + c4 * 4);
    }
    __syncthreads();
#pragma unroll
    for (int k4 = 0; k4 < BK / 4; k4++) {
      float4 wa[4][2];
#pragma unroll
      for (int kk = 0; kk < 4; kk++) {
        wa[kk][0] = *(const float4*)&wsh[k4 * 4 + kk][tx * 8];
        wa[kk][1] = *(const float4*)&wsh[k4 * 4 + kk][tx * 8 + 4];
      }
#pragma unroll
      for (int i = 0; i < 8; i++) {
        float4 xv = *(const float4*)&xs[ty + 32 * i][k4 * 4];
#pragma unroll
        for (int h = 0; h < 2; h++) {
          acc[i][h * 4 + 0] += xv.x * wa[0][h].x + xv.y * wa[1][h].x + xv.z * wa[2][h].x + xv.w * wa[3][h].x;
          acc[i][h * 4 + 1] += xv.x * wa[0][h].y + xv.y * wa[1][h].y + xv.z * wa[2][h].y + xv.w * wa[3][h].y;
          acc[i][h * 4 + 2] += xv.x * wa[0][h].z + xv.y * wa[1][h].z + xv.z * wa[2][h].z + xv.w * wa[3][h].z;
          acc[i][h * 4 + 3] += xv.x * wa[0][h].w + xv.y * wa[1][h].w + xv.z * wa[2][h].w + xv.w * wa[3][h].w;
        }
      }
    }
    __syncthreads();
  }
#pragma unroll
  for (int i = 0; i < 8; i++) {
    int t = tb * BM + ty + 32 * i;
    float* dst = part + ((size_t)t * KS + ks) * EE + tx * 8;
    *(float4*)dst       = make_float4(acc[i][0], acc[i][1], acc[i][2], acc[i][3]);
    *(float4*)(dst + 4) = make_float4(acc[i][4], acc[i][5], acc[i][6], acc[i][7]);
  }
}

// ---------------- per-token: softmax, top1 (gates), 2nd (logits), key ----------------
__global__ __launch_bounds__(256) void k_row(const float* __restrict__ part,
                                             const float* __restrict__ bias,
                                             float* __restrict__ gates,
                                             u64* __restrict__ keys,
                                             float2* __restrict__ g12,
                                             u32* __restrict__ cnt1) {
  int tid = threadIdx.x;
  int t = blockIdx.x * 4 + (tid >> 6);
  int e = tid & 63;
  const float* p = part + (size_t)t * KS * EE + e;
  float l = bias[e];
#pragma unroll
  for (int s = 0; s < KS; s++) l += p[s * EE];
  float m = l;
#pragma unroll
  for (int off = 32; off; off >>= 1) m = fmaxf(m, __shfl_xor(m, off));
  float ex = expf(l - m);
  float Z = ex;
#pragma unroll
  for (int off = 32; off; off >>= 1) Z += __shfl_xor(Z, off);
  float gate = ex / Z;
  gates[(size_t)t * 64 + e] = gate;
  float v1 = gate; int i1 = e;
#pragma unroll
  for (int off = 32; off; off >>= 1) {
    float ov = __shfl_xor(v1, off); int oi = __shfl_xor(i1, off);
    if (ov > v1 || (ov == v1 && oi < i1)) { v1 = ov; i1 = oi; }
  }
  float v2 = (e == i1) ? -FLT_MAX : l; int i2 = e;
#pragma unroll
  for (int off = 32; off; off >>= 1) {
    float ov = __shfl_xor(v2, off); int oi = __shfl_xor(i2, off);
    if (ov > v2 || (ov == v2 && oi < i2)) { v2 = ov; i2 = oi; }
  }
  float g1v = __shfl(gate, i1);
  float g2v = __shfl(gate, i2);
  if (e == 0) {
    u32 gb = __float_as_uint(v1);
    keys[t] = ((u64)(~gb) << 32) | ((u32)t << 12) | ((u32)i1 << 6) | (u32)i2;
    g12[t] = make_float2(g1v, g2v);
    atomicAdd(&cnt1[i1], 1u);
  }
}

// ---------------- pairwise rank counting ----------------
__global__ __launch_bounds__(256) void k_pair(const u64* __restrict__ keys,
                                              u32* __restrict__ r1a,
                                              u32* __restrict__ r2a) {
  __shared__ u64 sk[256];
  int tid = threadIdx.x;
  int t = blockIdx.x * 256 + tid;
  sk[tid] = keys[blockIdx.y * 256 + tid];
  __syncthreads();
  u64 myk = keys[t];
  u32 mye1 = (u32)((myk >> 6) & 63), mye2 = (u32)(myk & 63);
  u32 myt = (u32)t;
  u32 r1 = 0, r2 = 0;
  for (int j = 0; j < 256; j++) {
    u64 ks = sk[j];
    u32 se1 = (u32)((ks >> 6) & 63);
    u32 se2 = (u32)(ks & 63);
    u32 ss = (u32)((ks >> 12) & 4095);
    r1 += (se1 == mye1 && ks < myk) ? 1u : 0u;
    r2 += (se2 == mye2 && ss < myt) ? 1u : 0u;
  }
  if (r1) atomicAdd(&r1a[t], r1);
  if (r2) atomicAdd(&r2a[t], r2);
}

// ---------------- gates column partial sums ----------------
__global__ __launch_bounds__(256) void k_colsum(const float* __restrict__ gates,
                                                float* __restrict__ partial) {
  __shared__ float sh[256];
  int b = blockIdx.x;
  int tid = threadIdx.x;
  int lane = tid & 63, w = tid >> 6;
  float s = 0.f;
#pragma unroll
  for (int i = 0; i < 16; i++) {
    int t = b * 64 + w * 16 + i;
    s += gates[(size_t)t * 64 + lane];
  }
  sh[tid] = s;
  __syncthreads();
  if (tid < 64) {
    float p = sh[tid] + sh[tid + 64] + sh[tid + 128] + sh[tid + 192];
    partial[b * 64 + tid] = p;
  }
}

// ---------------- token slot info ----------------
__device__ __forceinline__ void load_tok(int tok,
    const u64* __restrict__ keys, const float2* __restrict__ g12,
    const u32* __restrict__ cnt1, const u32* __restrict__ r1a,
    const u32* __restrict__ r2a, int& o1, float& c1, int& o2, float& c2) {
  u64 k = keys[tok];
  int e1 = (int)((k >> 6) & 63), e2 = (int)(k & 63);
  u32 r1 = r1a[tok];
  u32 loc2 = cnt1[e2] + r2a[tok];
  float2 g = g12[tok];
  bool k1 = r1 < (u32)CAP;
  bool k2 = loc2 < (u32)CAP;
  float g1 = k1 ? g.x : 0.f;
  float g2 = k2 ? g.y : 0.f;
  float den = fmaxf(g1 + g2, 1.1920929e-07f);
  c1 = g1 / den;
  c2 = g2 / den;
  o1 = k1 ? e1 * CAP + (int)r1 : -1;
  o2 = k2 ? e2 * CAP + (int)loc2 : -1;
}

// ---------------- fused zero-fill + scatter + l_aux (writes ALL of d_out) ----------------
__global__ __launch_bounds__(256) void k_fill(const u64* __restrict__ keys,
                                              const float2* __restrict__ g12,
                                              const u32* __restrict__ cnt1,
                                              const u32* __restrict__ r1a,
                                              const u32* __restrict__ r2a,
                                              const float* __restrict__ partial,
                                              float* __restrict__ out) {
  int b = blockIdx.x;
  int tid = threadIdx.x;
  bool isDisp = b >= SS;
  int t = isDisp ? b - SS : b;

  int o1, o2; float c1, c2;
  load_tok(t, keys, g12, cnt1, r1a, r2a, o1, c1, o2, c2);
  float v1 = isDisp ? 1.f : c1;
  float v2 = isDisp ? 1.f : c2;

  int p0 = -1, p1 = -1, p2 = -1;
  float q0 = 0.f, q1 = 0.f, q2 = 0.f;
  if (o1 >= 0 && o1 < ROW - 1) { p0 = o1 + 1; q0 = v1; }
  if (o2 >= 0 && o2 < ROW - 1) { p1 = o2 + 1; q1 = v2; }

  if (b == 0) {
    float term = 0.f;
    if (tid < 64) {
      float s = 0.f;
#pragma unroll 8
      for (int bb = 0; bb < 64; bb++) s += partial[bb * 64 + tid];
      float me = s * (1.0f / SS);
      float ce = (float)cnt1[tid] * (1.0f / SS);
      term = me * ce;
#pragma unroll
      for (int off = 32; off; off >>= 1) term += __shfl_xor(term, off);
    }
    p2 = 0; q2 = term * (float)EE * 0.01f;
  } else {
    bool prevIsComb = (!isDisp) || (b == SS);
    int tprev = (b == SS) ? SS - 1 : t - 1;
    int po1, po2; float pc1, pc2;
    load_tok(tprev, keys, g12, cnt1, r1a, r2a, po1, pc1, po2, pc2);
    if (po1 == ROW - 1)      { p2 = 0; q2 = prevIsComb ? pc1 : 1.f; }
    else if (po2 == ROW - 1) { p2 = 0; q2 = prevIsComb ? pc2 : 1.f; }
  }

  float* dst = out + (size_t)b * ROW;
#pragma unroll
  for (int i = 0; i < 8; i++) {
    int l0 = (tid + i * 256) * 4;
    float4 v;
    int la = l0, lb = l0 + 1, lc = l0 + 2, ld = l0 + 3;
    v.x = (la == p0) ? q0 : (la == p1) ? q1 : (la == p2) ? q2 : 0.f;
    v.y = (lb == p0) ? q0 : (lb == p1) ? q1 : (lb == p2) ? q2 : 0.f;
    v.z = (lc == p0) ? q0 : (lc == p1) ? q1 : (lc == p2) ? q2 : 0.f;
    v.w = (ld == p0) ? q0 : (ld == p1) ? q1 : (ld == p2) ? q2 : 0.f;
    *(float4*)(dst + l0) = v;
  }

  if (b == 2 * SS - 1 && tid == 0) {
    float tv = (o1 == ROW - 1 || o2 == ROW - 1) ? 1.f : 0.f;
    out[2 * SEC] = tv;
  }
}

extern "C" void kernel_launch(void* const* d_in, const int* in_sizes, int n_in,
                              void* d_out, int out_size, void* d_ws, size_t ws_size,
                              hipStream_t stream) {
  const float* x = (const float*)d_in[0];
  const float* W = (const float*)d_in[1];
  const float* bias = (const float*)d_in[2];
  float* out = (float*)d_out;

  // workspace layout
  float* Wt = (float*)d_ws;                    // 262144 floats (1 MB)
  float* part = Wt + 262144;                   // SS*KS*EE = 8388608 floats (32 MB)
  float* gates = part + (size_t)SS * KS * EE;  // 262144 floats (1 MB)
  u64* keys = (u64*)(gates + (size_t)SE);      // 4096 u64
  float2* g12 = (float2*)(keys + SS);          // 4096 float2
  u32* cnt1 = (u32*)(g12 + SS);                // 64
  u32* r1a = cnt1 + 64;                        // 4096
  u32* r2a = r1a + SS;                         // 4096
  float* partial = (float*)(r2a + SS);         // 64*64 floats

  k_transpose<<<64, 256, 0, stream>>>(W, Wt, cnt1);
  k_gemm<<<dim3(SS / BM, KS, ZREP), 256, 0, stream>>>(x, Wt, part);
  k_row<<<SS / 4, 256, 0, stream>>>(part, bias, gates, keys, g12, cnt1);
  k_pair<<<dim3(16, 16), 256, 0, stream>>>(keys, r1a, r2a);
  k_colsum<<<64, 256, 0, stream>>>(gates, partial);
  k_fill<<<2 * SS, 256, 0, stream>>>(keys, g12, cnt1, r1a, r2a, partial, out);
}

// Round 6
// 952.551 us; speedup vs baseline: 2.5544x; 2.5544x over previous
//
#include <hip/hip_runtime.h>
#include <hip/hip_bf16.h>
#include <float.h>

#define SS 4096
#define EE 64
#define DD 4096
#define CAP 128
#define SE (SS*EE)                    // 262144
#define ROW 8192                      // EE*CAP floats per token row
#define KS 16                         // split-K slices (256 k each)
#define BM 64                         // token tile
#define BK 64                         // k sub-tile
#define ZREP 12                       // DIAGNOSTIC: replicas write DISTINCT buffers
static const size_t SEC = (size_t)SS * EE * CAP;  // 33554432
static const size_t PART_SLICE = (size_t)SS * KS * EE;  // 4194304 floats

typedef unsigned long long u64;
typedef unsigned int u32;

// ---------------- W transpose + zero flag arrays ----------------
__global__ __launch_bounds__(256) void k_transpose(const float* __restrict__ W,
                                                   float* __restrict__ Wt,
                                                   u32* __restrict__ zbase) {
  int gid = blockIdx.x * 256 + threadIdx.x;
  if (gid < 64 + 2 * SS) zbase[gid] = 0u;

  __shared__ float t[64][65];
  int k0 = blockIdx.x * 64;
  int tid = threadIdx.x;
#pragma unroll
  for (int i = 0; i < 4; i++) {
    int f = tid + i * 256;
    int e = f >> 4, c4 = f & 15;
    float4 v = *(const float4*)(W + (size_t)e * DD + k0 + c4 * 4);
    t[e][c4 * 4 + 0] = v.x; t[e][c4 * 4 + 1] = v.y;
    t[e][c4 * 4 + 2] = v.z; t[e][c4 * 4 + 3] = v.w;
  }
  __syncthreads();
#pragma unroll
  for (int i = 0; i < 4; i++) {
    int f = tid + i * 256;
    int r = f >> 4, e4 = f & 15;
    float4 o;
    o.x = t[e4 * 4 + 0][r]; o.y = t[e4 * 4 + 1][r];
    o.z = t[e4 * 4 + 2][r]; o.w = t[e4 * 4 + 3][r];
    *(float4*)(Wt + (size_t)(k0 + r) * 64 + e4 * 4) = o;
  }
}

// ---------------- GEMM v4: lane=expert, LDS-broadcast x ----------------
// grid (SS/BM=64, KS=16, ZREP). Wave w owns tokens [w*16, w*16+16).
// acc[i] = logit partial for token (tb*64+w*16+i), expert = lane.
// x reads from LDS are wave-uniform (broadcast, conflict-free);
// W column reads are lane%32 -> 2-way (free).
__global__ __launch_bounds__(256) void k_gemm(const float* __restrict__ x,
                                              const float* __restrict__ Wt,
                                              float* __restrict__ part_all) {
  __shared__ float xs[BM][BK];      // 16 KB
  __shared__ float wsh[BK][EE];     // 16 KB
  int tb = blockIdx.x;
  int ks = blockIdx.y;
  float* part = part_all + (size_t)blockIdx.z * PART_SLICE;
  int tid = threadIdx.x;
  int lane = tid & 63, w = tid >> 6;
  float acc[16] = {};
#pragma unroll 1
  for (int kt = 0; kt < 256 / BK; kt++) {   // 4 sub-tiles of the 256-wide slice
    int k0 = ks * 256 + kt * BK;
    // stage x: 64x64 floats, 4 float4/thread, coalesced
#pragma unroll
    for (int i = 0; i < 4; i++) {
      int q = tid + i * 256;
      int r = q >> 4, c4 = q & 15;
      *(float4*)&xs[r][c4 * 4] =
          *(const float4*)(x + (size_t)(tb * BM + r) * DD + k0 + c4 * 4);
    }
    // stage w: 64x64 floats
#pragma unroll
    for (int i = 0; i < 4; i++) {
      int q = tid + i * 256;
      int r = q >> 4, c4 = q & 15;
      *(float4*)&wsh[r][c4 * 4] = *(const float4*)(Wt + (size_t)(k0 + r) * EE + c4 * 4);
    }
    __syncthreads();
#pragma unroll
    for (int kq = 0; kq < BK / 4; kq++) {
      float w0 = wsh[kq * 4 + 0][lane];
      float w1 = wsh[kq * 4 + 1][lane];
      float w2 = wsh[kq * 4 + 2][lane];
      float w3 = wsh[kq * 4 + 3][lane];
#pragma unroll
      for (int i = 0; i < 16; i++) {
        float4 xv = *(const float4*)&xs[w * 16 + i][kq * 4];
        acc[i] += xv.x * w0 + xv.y * w1 + xv.z * w2 + xv.w * w3;
      }
    }
    __syncthreads();
  }
#pragma unroll
  for (int i = 0; i < 16; i++) {
    int t = tb * BM + w * 16 + i;
    part[((size_t)t * KS + ks) * EE + lane] = acc[i];
  }
}

// ---------------- per-token: softmax, top1 (gates), 2nd (logits), key ----------------
__global__ __launch_bounds__(256) void k_row(const float* __restrict__ part,
                                             const float* __restrict__ bias,
                                             float* __restrict__ gates,
                                             u64* __restrict__ keys,
                                             float2* __restrict__ g12,
                                             u32* __restrict__ cnt1) {
  int tid = threadIdx.x;
  int t = blockIdx.x * 4 + (tid >> 6);
  int e = tid & 63;
  const float* p = part + (size_t)t * KS * EE + e;
  float l = bias[e];
#pragma unroll
  for (int s = 0; s < KS; s++) l += p[s * EE];
  float m = l;
#pragma unroll
  for (int off = 32; off; off >>= 1) m = fmaxf(m, __shfl_xor(m, off));
  float ex = expf(l - m);
  float Z = ex;
#pragma unroll
  for (int off = 32; off; off >>= 1) Z += __shfl_xor(Z, off);
  float gate = ex / Z;
  gates[(size_t)t * 64 + e] = gate;
  float v1 = gate; int i1 = e;
#pragma unroll
  for (int off = 32; off; off >>= 1) {
    float ov = __shfl_xor(v1, off); int oi = __shfl_xor(i1, off);
    if (ov > v1 || (ov == v1 && oi < i1)) { v1 = ov; i1 = oi; }
  }
  float v2 = (e == i1) ? -FLT_MAX : l; int i2 = e;
#pragma unroll
  for (int off = 32; off; off >>= 1) {
    float ov = __shfl_xor(v2, off); int oi = __shfl_xor(i2, off);
    if (ov > v2 || (ov == v2 && oi < i2)) { v2 = ov; i2 = oi; }
  }
  float g1v = __shfl(gate, i1);
  float g2v = __shfl(gate, i2);
  if (e == 0) {
    u32 gb = __float_as_uint(v1);
    keys[t] = ((u64)(~gb) << 32) | ((u32)t << 12) | ((u32)i1 << 6) | (u32)i2;
    g12[t] = make_float2(g1v, g2v);
    atomicAdd(&cnt1[i1], 1u);
  }
}

// ---------------- pairwise rank counting ----------------
__global__ __launch_bounds__(256) void k_pair(const u64* __restrict__ keys,
                                              u32* __restrict__ r1a,
                                              u32* __restrict__ r2a) {
  __shared__ u64 sk[256];
  int tid = threadIdx.x;
  int t = blockIdx.x * 256 + tid;
  sk[tid] = keys[blockIdx.y * 256 + tid];
  __syncthreads();
  u64 myk = keys[t];
  u32 mye1 = (u32)((myk >> 6) & 63), mye2 = (u32)(myk & 63);
  u32 myt = (u32)t;
  u32 r1 = 0, r2 = 0;
  for (int j = 0; j < 256; j++) {
    u64 ks = sk[j];
    u32 se1 = (u32)((ks >> 6) & 63);
    u32 se2 = (u32)(ks & 63);
    u32 ss = (u32)((ks >> 12) & 4095);
    r1 += (se1 == mye1 && ks < myk) ? 1u : 0u;
    r2 += (se2 == mye2 && ss < myt) ? 1u : 0u;
  }
  if (r1) atomicAdd(&r1a[t], r1);
  if (r2) atomicAdd(&r2a[t], r2);
}

// ---------------- gates column partial sums ----------------
__global__ __launch_bounds__(256) void k_colsum(const float* __restrict__ gates,
                                                float* __restrict__ partial) {
  __shared__ float sh[256];
  int b = blockIdx.x;
  int tid = threadIdx.x;
  int lane = tid & 63, w = tid >> 6;
  float s = 0.f;
#pragma unroll
  for (int i = 0; i < 16; i++) {
    int t = b * 64 + w * 16 + i;
    s += gates[(size_t)t * 64 + lane];
  }
  sh[tid] = s;
  __syncthreads();
  if (tid < 64) {
    float p = sh[tid] + sh[tid + 64] + sh[tid + 128] + sh[tid + 192];
    partial[b * 64 + tid] = p;
  }
}

// ---------------- token slot info ----------------
__device__ __forceinline__ void load_tok(int tok,
    const u64* __restrict__ keys, const float2* __restrict__ g12,
    const u32* __restrict__ cnt1, const u32* __restrict__ r1a,
    const u32* __restrict__ r2a, int& o1, float& c1, int& o2, float& c2) {
  u64 k = keys[tok];
  int e1 = (int)((k >> 6) & 63), e2 = (int)(k & 63);
  u32 r1 = r1a[tok];
  u32 loc2 = cnt1[e2] + r2a[tok];
  float2 g = g12[tok];
  bool k1 = r1 < (u32)CAP;
  bool k2 = loc2 < (u32)CAP;
  float g1 = k1 ? g.x : 0.f;
  float g2 = k2 ? g.y : 0.f;
  float den = fmaxf(g1 + g2, 1.1920929e-07f);
  c1 = g1 / den;
  c2 = g2 / den;
  o1 = k1 ? e1 * CAP + (int)r1 : -1;
  o2 = k2 ? e2 * CAP + (int)loc2 : -1;
}

// ---------------- fused zero-fill + scatter + l_aux (writes ALL of d_out) ----------------
__global__ __launch_bounds__(256) void k_fill(const u64* __restrict__ keys,
                                              const float2* __restrict__ g12,
                                              const u32* __restrict__ cnt1,
                                              const u32* __restrict__ r1a,
                                              const u32* __restrict__ r2a,
                                              const float* __restrict__ partial,
                                              float* __restrict__ out) {
  int b = blockIdx.x;
  int tid = threadIdx.x;
  bool isDisp = b >= SS;
  int t = isDisp ? b - SS : b;

  int o1, o2; float c1, c2;
  load_tok(t, keys, g12, cnt1, r1a, r2a, o1, c1, o2, c2);
  float v1 = isDisp ? 1.f : c1;
  float v2 = isDisp ? 1.f : c2;

  int p0 = -1, p1 = -1, p2 = -1;
  float q0 = 0.f, q1 = 0.f, q2 = 0.f;
  if (o1 >= 0 && o1 < ROW - 1) { p0 = o1 + 1; q0 = v1; }
  if (o2 >= 0 && o2 < ROW - 1) { p1 = o2 + 1; q1 = v2; }

  if (b == 0) {
    float term = 0.f;
    if (tid < 64) {
      float s = 0.f;
#pragma unroll 8
      for (int bb = 0; bb < 64; bb++) s += partial[bb * 64 + tid];
      float me = s * (1.0f / SS);
      float ce = (float)cnt1[tid] * (1.0f / SS);
      term = me * ce;
#pragma unroll
      for (int off = 32; off; off >>= 1) term += __shfl_xor(term, off);
    }
    p2 = 0; q2 = term * (float)EE * 0.01f;
  } else {
    bool prevIsComb = (!isDisp) || (b == SS);
    int tprev = (b == SS) ? SS - 1 : t - 1;
    int po1, po2; float pc1, pc2;
    load_tok(tprev, keys, g12, cnt1, r1a, r2a, po1, pc1, po2, pc2);
    if (po1 == ROW - 1)      { p2 = 0; q2 = prevIsComb ? pc1 : 1.f; }
    else if (po2 == ROW - 1) { p2 = 0; q2 = prevIsComb ? pc2 : 1.f; }
  }

  float* dst = out + (size_t)b * ROW;
#pragma unroll
  for (int i = 0; i < 8; i++) {
    int l0 = (tid + i * 256) * 4;
    float4 v;
    int la = l0, lb = l0 + 1, lc = l0 + 2, ld = l0 + 3;
    v.x = (la == p0) ? q0 : (la == p1) ? q1 : (la == p2) ? q2 : 0.f;
    v.y = (lb == p0) ? q0 : (lb == p1) ? q1 : (lb == p2) ? q2 : 0.f;
    v.z = (lc == p0) ? q0 : (lc == p1) ? q1 : (lc == p2) ? q2 : 0.f;
    v.w = (ld == p0) ? q0 : (ld == p1) ? q1 : (ld == p2) ? q2 : 0.f;
    *(float4*)(dst + l0) = v;
  }

  if (b == 2 * SS - 1 && tid == 0) {
    float tv = (o1 == ROW - 1 || o2 == ROW - 1) ? 1.f : 0.f;
    out[2 * SEC] = tv;
  }
}

extern "C" void kernel_launch(void* const* d_in, const int* in_sizes, int n_in,
                              void* d_out, int out_size, void* d_ws, size_t ws_size,
                              hipStream_t stream) {
  const float* x = (const float*)d_in[0];
  const float* W = (const float*)d_in[1];
  const float* bias = (const float*)d_in[2];
  float* out = (float*)d_out;

  // workspace layout
  float* Wt = (float*)d_ws;                     // 262144 floats (1 MB)
  float* part_all = Wt + 262144;                // ZREP * 16 MB slices
  float* gates = part_all + ZREP * PART_SLICE;  // 262144 floats (1 MB)
  u64* keys = (u64*)(gates + (size_t)SE);       // 4096 u64
  float2* g12 = (float2*)(keys + SS);           // 4096 float2
  u32* cnt1 = (u32*)(g12 + SS);                 // 64
  u32* r1a = cnt1 + 64;                         // 4096
  u32* r2a = r1a + SS;                          // 4096
  float* partial = (float*)(r2a + SS);          // 64*64 floats

  k_transpose<<<64, 256, 0, stream>>>(W, Wt, cnt1);
  k_gemm<<<dim3(SS / BM, KS, ZREP), 256, 0, stream>>>(x, Wt, part_all);
  k_row<<<SS / 4, 256, 0, stream>>>(part_all, bias, gates, keys, g12, cnt1);
  k_pair<<<dim3(16, 16), 256, 0, stream>>>(keys, r1a, r2a);
  k_colsum<<<64, 256, 0, stream>>>(gates, partial);
  k_fill<<<2 * SS, 256, 0, stream>>>(keys, g12, cnt1, r1a, r2a, partial, out);
}

// Round 7
// 157.366 us; speedup vs baseline: 15.4619x; 6.0531x over previous
//
#include <hip/hip_runtime.h>
#include <hip/hip_bf16.h>
#include <float.h>

#define SS 4096
#define EE 64
#define DD 4096
#define CAP 128
#define SE (SS*EE)                    // 262144
#define ROW 8192                      // EE*CAP floats per token row
#define KS 16                         // split-K slices (256 k each)
#define BK 64                         // k sub-tile
static const size_t SEC = (size_t)SS * EE * CAP;  // 33554432

typedef unsigned long long u64;
typedef unsigned int u32;

// ---------------- W transpose + zero flag arrays ----------------
__global__ __launch_bounds__(256) void k_transpose(const float* __restrict__ W,
                                                   float* __restrict__ Wt,
                                                   u32* __restrict__ zbase) {
  int gid = blockIdx.x * 256 + threadIdx.x;
  if (gid < 64 + 2 * SS) zbase[gid] = 0u;

  __shared__ float t[64][65];
  int k0 = blockIdx.x * 64;
  int tid = threadIdx.x;
#pragma unroll
  for (int i = 0; i < 4; i++) {
    int f = tid + i * 256;
    int e = f >> 4, c4 = f & 15;
    float4 v = *(const float4*)(W + (size_t)e * DD + k0 + c4 * 4);
    t[e][c4 * 4 + 0] = v.x; t[e][c4 * 4 + 1] = v.y;
    t[e][c4 * 4 + 2] = v.z; t[e][c4 * 4 + 3] = v.w;
  }
  __syncthreads();
#pragma unroll
  for (int i = 0; i < 4; i++) {
    int f = tid + i * 256;
    int r = f >> 4, e4 = f & 15;
    float4 o;
    o.x = t[e4 * 4 + 0][r]; o.y = t[e4 * 4 + 1][r];
    o.z = t[e4 * 4 + 2][r]; o.w = t[e4 * 4 + 3][r];
    *(float4*)(Wt + (size_t)(k0 + r) * 64 + e4 * 4) = o;
  }
}

// ---------------- GEMM v5: 64x64 tile, 4 tok x 4 exp / thread, KS=16 ----------------
// grid (64, 16) = 1024 blocks (4/CU, LDS-capped), 256 threads.
// All LDS accesses <=2-way (free): xs reads ty-pairs 2-way/broadcast, w reads
// tx 2-way/broadcast, staging writes 2-way.
__global__ __launch_bounds__(256) void k_gemm(const float* __restrict__ x,
                                              const float* __restrict__ Wt,
                                              float* __restrict__ part) {
  __shared__ float xs[64][68];   // padded
  __shared__ float wsh[64][64];
  int tb = blockIdx.x;   // token tile (64 tokens)
  int ks = blockIdx.y;   // k slice (256 wide)
  int tid = threadIdx.x;
  int tx = tid & 15, ty = tid >> 4;
  float acc[4][4] = {};
#pragma unroll 1
  for (int kt = 0; kt < 256 / BK; kt++) {   // 4 sub-tiles
    int k0 = ks * 256 + kt * BK;
#pragma unroll
    for (int i = 0; i < 4; i++) {
      int f = tid + i * 256;
      int r = f >> 4, c4 = f & 15;
      *(float4*)&xs[r][c4 * 4] =
          *(const float4*)(x + (size_t)(tb * 64 + r) * DD + k0 + c4 * 4);
    }
#pragma unroll
    for (int i = 0; i < 4; i++) {
      int f = tid + i * 256;
      int r = f >> 4, c4 = f & 15;
      *(float4*)&wsh[r][c4 * 4] = *(const float4*)(Wt + (size_t)(k0 + r) * EE + c4 * 4);
    }
    __syncthreads();
#pragma unroll
    for (int k4 = 0; k4 < BK / 4; k4++) {
      float xa[4][4], wa[4][4];
#pragma unroll
      for (int i = 0; i < 4; i++) {
        float4 v = *(const float4*)&xs[ty * 4 + i][k4 * 4];
        xa[i][0] = v.x; xa[i][1] = v.y; xa[i][2] = v.z; xa[i][3] = v.w;
      }
#pragma unroll
      for (int kk = 0; kk < 4; kk++) {
        float4 v = *(const float4*)&wsh[k4 * 4 + kk][tx * 4];
        wa[kk][0] = v.x; wa[kk][1] = v.y; wa[kk][2] = v.z; wa[kk][3] = v.w;
      }
#pragma unroll
      for (int i = 0; i < 4; i++)
#pragma unroll
        for (int j = 0; j < 4; j++)
          acc[i][j] += xa[i][0] * wa[0][j] + xa[i][1] * wa[1][j]
                     + xa[i][2] * wa[2][j] + xa[i][3] * wa[3][j];
    }
    __syncthreads();
  }
#pragma unroll
  for (int i = 0; i < 4; i++) {
    *(float4*)(part + (((size_t)tb * 64 + ty * 4 + i) * KS + ks) * EE + tx * 4) =
        make_float4(acc[i][0], acc[i][1], acc[i][2], acc[i][3]);
  }
}

// ---------------- per-token: softmax, top1 (gates), 2nd (logits), key ----------------
__global__ __launch_bounds__(256) void k_row(const float* __restrict__ part,
                                             const float* __restrict__ bias,
                                             float* __restrict__ gates,
                                             u64* __restrict__ keys,
                                             float2* __restrict__ g12,
                                             u32* __restrict__ cnt1) {
  int tid = threadIdx.x;
  int t = blockIdx.x * 4 + (tid >> 6);
  int e = tid & 63;
  const float* p = part + (size_t)t * KS * EE + e;
  float l = bias[e];
#pragma unroll
  for (int s = 0; s < KS; s++) l += p[s * EE];
  float m = l;
#pragma unroll
  for (int off = 32; off; off >>= 1) m = fmaxf(m, __shfl_xor(m, off));
  float ex = expf(l - m);
  float Z = ex;
#pragma unroll
  for (int off = 32; off; off >>= 1) Z += __shfl_xor(Z, off);
  float gate = ex / Z;
  gates[(size_t)t * 64 + e] = gate;
  float v1 = gate; int i1 = e;
#pragma unroll
  for (int off = 32; off; off >>= 1) {
    float ov = __shfl_xor(v1, off); int oi = __shfl_xor(i1, off);
    if (ov > v1 || (ov == v1 && oi < i1)) { v1 = ov; i1 = oi; }
  }
  float v2 = (e == i1) ? -FLT_MAX : l; int i2 = e;
#pragma unroll
  for (int off = 32; off; off >>= 1) {
    float ov = __shfl_xor(v2, off); int oi = __shfl_xor(i2, off);
    if (ov > v2 || (ov == v2 && oi < i2)) { v2 = ov; i2 = oi; }
  }
  float g1v = __shfl(gate, i1);
  float g2v = __shfl(gate, i2);
  if (e == 0) {
    u32 gb = __float_as_uint(v1);
    keys[t] = ((u64)(~gb) << 32) | ((u32)t << 12) | ((u32)i1 << 6) | (u32)i2;
    g12[t] = make_float2(g1v, g2v);
    atomicAdd(&cnt1[i1], 1u);
  }
}

// ---------------- pairwise rank counting ----------------
__global__ __launch_bounds__(256) void k_pair(const u64* __restrict__ keys,
                                              u32* __restrict__ r1a,
                                              u32* __restrict__ r2a) {
  __shared__ u64 sk[256];
  int tid = threadIdx.x;
  int t = blockIdx.x * 256 + tid;
  sk[tid] = keys[blockIdx.y * 256 + tid];
  __syncthreads();
  u64 myk = keys[t];
  u32 mye1 = (u32)((myk >> 6) & 63), mye2 = (u32)(myk & 63);
  u32 myt = (u32)t;
  u32 r1 = 0, r2 = 0;
  for (int j = 0; j < 256; j++) {
    u64 ks = sk[j];
    u32 se1 = (u32)((ks >> 6) & 63);
    u32 se2 = (u32)(ks & 63);
    u32 ss = (u32)((ks >> 12) & 4095);
    r1 += (se1 == mye1 && ks < myk) ? 1u : 0u;
    r2 += (se2 == mye2 && ss < myt) ? 1u : 0u;
  }
  if (r1) atomicAdd(&r1a[t], r1);
  if (r2) atomicAdd(&r2a[t], r2);
}

// ---------------- gates column partial sums ----------------
__global__ __launch_bounds__(256) void k_colsum(const float* __restrict__ gates,
                                                float* __restrict__ partial) {
  __shared__ float sh[256];
  int b = blockIdx.x;
  int tid = threadIdx.x;
  int lane = tid & 63, w = tid >> 6;
  float s = 0.f;
#pragma unroll
  for (int i = 0; i < 16; i++) {
    int t = b * 64 + w * 16 + i;
    s += gates[(size_t)t * 64 + lane];
  }
  sh[tid] = s;
  __syncthreads();
  if (tid < 64) {
    float p = sh[tid] + sh[tid + 64] + sh[tid + 128] + sh[tid + 192];
    partial[b * 64 + tid] = p;
  }
}

// ---------------- token slot info ----------------
__device__ __forceinline__ void load_tok(int tok,
    const u64* __restrict__ keys, const float2* __restrict__ g12,
    const u32* __restrict__ cnt1, const u32* __restrict__ r1a,
    const u32* __restrict__ r2a, int& o1, float& c1, int& o2, float& c2) {
  u64 k = keys[tok];
  int e1 = (int)((k >> 6) & 63), e2 = (int)(k & 63);
  u32 r1 = r1a[tok];
  u32 loc2 = cnt1[e2] + r2a[tok];
  float2 g = g12[tok];
  bool k1 = r1 < (u32)CAP;
  bool k2 = loc2 < (u32)CAP;
  float g1 = k1 ? g.x : 0.f;
  float g2 = k2 ? g.y : 0.f;
  float den = fmaxf(g1 + g2, 1.1920929e-07f);
  c1 = g1 / den;
  c2 = g2 / den;
  o1 = k1 ? e1 * CAP + (int)r1 : -1;
  o2 = k2 ? e2 * CAP + (int)loc2 : -1;
}

// ---------------- fused zero-fill + scatter + l_aux (writes ALL of d_out) ----------------
__global__ __launch_bounds__(256) void k_fill(const u64* __restrict__ keys,
                                              const float2* __restrict__ g12,
                                              const u32* __restrict__ cnt1,
                                              const u32* __restrict__ r1a,
                                              const u32* __restrict__ r2a,
                                              const float* __restrict__ partial,
                                              float* __restrict__ out) {
  int b = blockIdx.x;
  int tid = threadIdx.x;
  bool isDisp = b >= SS;
  int t = isDisp ? b - SS : b;

  int o1, o2; float c1, c2;
  load_tok(t, keys, g12, cnt1, r1a, r2a, o1, c1, o2, c2);
  float v1 = isDisp ? 1.f : c1;
  float v2 = isDisp ? 1.f : c2;

  int p0 = -1, p1 = -1, p2 = -1;
  float q0 = 0.f, q1 = 0.f, q2 = 0.f;
  if (o1 >= 0 && o1 < ROW - 1) { p0 = o1 + 1; q0 = v1; }
  if (o2 >= 0 && o2 < ROW - 1) { p1 = o2 + 1; q1 = v2; }

  if (b == 0) {
    float term = 0.f;
    if (tid < 64) {
      float s = 0.f;
#pragma unroll 8
      for (int bb = 0; bb < 64; bb++) s += partial[bb * 64 + tid];
      float me = s * (1.0f / SS);
      float ce = (float)cnt1[tid] * (1.0f / SS);
      term = me * ce;
#pragma unroll
      for (int off = 32; off; off >>= 1) term += __shfl_xor(term, off);
    }
    p2 = 0; q2 = term * (float)EE * 0.01f;
  } else {
    bool prevIsComb = (!isDisp) || (b == SS);
    int tprev = (b == SS) ? SS - 1 : t - 1;
    int po1, po2; float pc1, pc2;
    load_tok(tprev, keys, g12, cnt1, r1a, r2a, po1, pc1, po2, pc2);
    if (po1 == ROW - 1)      { p2 = 0; q2 = prevIsComb ? pc1 : 1.f; }
    else if (po2 == ROW - 1) { p2 = 0; q2 = prevIsComb ? pc2 : 1.f; }
  }

  float* dst = out + (size_t)b * ROW;
#pragma unroll
  for (int i = 0; i < 8; i++) {
    int l0 = (tid + i * 256) * 4;
    float4 v;
    int la = l0, lb = l0 + 1, lc = l0 + 2, ld = l0 + 3;
    v.x = (la == p0) ? q0 : (la == p1) ? q1 : (la == p2) ? q2 : 0.f;
    v.y = (lb == p0) ? q0 : (lb == p1) ? q1 : (lb == p2) ? q2 : 0.f;
    v.z = (lc == p0) ? q0 : (lc == p1) ? q1 : (lc == p2) ? q2 : 0.f;
    v.w = (ld == p0) ? q0 : (ld == p1) ? q1 : (ld == p2) ? q2 : 0.f;
    *(float4*)(dst + l0) = v;
  }

  if (b == 2 * SS - 1 && tid == 0) {
    float tv = (o1 == ROW - 1 || o2 == ROW - 1) ? 1.f : 0.f;
    out[2 * SEC] = tv;
  }
}

extern "C" void kernel_launch(void* const* d_in, const int* in_sizes, int n_in,
                              void* d_out, int out_size, void* d_ws, size_t ws_size,
                              hipStream_t stream) {
  const float* x = (const float*)d_in[0];
  const float* W = (const float*)d_in[1];
  const float* bias = (const float*)d_in[2];
  float* out = (float*)d_out;

  // workspace layout
  float* Wt = (float*)d_ws;                     // 262144 floats (1 MB)
  float* part = Wt + 262144;                    // SS*KS*EE = 4194304 floats (16 MB)
  float* gates = part + (size_t)SS * KS * EE;   // 262144 floats (1 MB)
  u64* keys = (u64*)(gates + (size_t)SE);       // 4096 u64
  float2* g12 = (float2*)(keys + SS);           // 4096 float2
  u32* cnt1 = (u32*)(g12 + SS);                 // 64
  u32* r1a = cnt1 + 64;                         // 4096
  u32* r2a = r1a + SS;                          // 4096
  float* partial = (float*)(r2a + SS);          // 64*64 floats

  k_transpose<<<64, 256, 0, stream>>>(W, Wt, cnt1);
  k_gemm<<<dim3(64, KS), 256, 0, stream>>>(x, Wt, part);
  k_row<<<SS / 4, 256, 0, stream>>>(part, bias, gates, keys, g12, cnt1);
  k_pair<<<dim3(16, 16), 256, 0, stream>>>(keys, r1a, r2a);
  k_colsum<<<64, 256, 0, stream>>>(gates, partial);
  k_fill<<<2 * SS, 256, 0, stream>>>(keys, g12, cnt1, r1a, r2a, partial, out);
}